// Round 5
// baseline (388.018 us; speedup 1.0000x reference)
//
#include <hip/hip_runtime.h>
#include <cfloat>
#include <math.h>

// Brute-force exact-replication KNN (k=10, +self) over 16384 3-D points, two
// instances, then M_i = max_j feats[nbr_rank_j, j-1], out = [feats | M-feats].
//
// NUMERICS ARE FROZEN (round-3 pass, absmax 0.0): XLA-consistent fp32 chains
//   sq  = fma(z,z, fma(y,y, rn(x*x)))
//   dot = fma(z,z', fma(y,y', rn(x*x')))   [same chain -> d_ii == 0.0 exactly]
//   d   = rn(rn(sq_i + sq_j) - rn(2*dot))
// Stable ascending-index insert == jax top_k tie-break; positional rank-0
// drop; M-v == subtract-then-max by rounding monotonicity. Do not alter.
//
// Round 5 (perf only): cut VALU issue ~2x.
//  - v_pk_{mul,add,fma}_f32 (VOP3P packed fp32, IEEE rn per half — bitwise
//    identical chains): each lane evaluates candidates (2*lane, 2*lane+1).
//    Final sub as pk_fma(dot,-2,sum) == rn(sum - rn(2*dot)) since 2*dot is
//    exact in fp32 (pure exponent shift, no overflow at these magnitudes).
//  - SoA LDS tiles -> one ds_read_b64 per coord per candidate pair
//    (2-way bank aliasing is free on gfx950).
//  - Insert path: uniform-lane broadcasts via v_readlane (not __shfl),
//    worst kept uniform, shfl_up via raw ds_bpermute w/ hoisted address.
//    Even/odd masks merged in ascending global candidate index, preserving
//    the stable tie-break exactly.

#define N_PTS    16384
#define C_FEAT   64
#define KK       11          // K+1 including self
#define TILE     1024        // candidates staged per LDS tile (12 KB SoA)
#define WQ       4           // queries processed concurrently per wave
#define NWAVES   4
#define NTHREADS (NWAVES * 64)
#define QPB      (NWAVES * WQ)           // 16 queries per block

typedef float v2f __attribute__((ext_vector_type(2)));

static __device__ __forceinline__ v2f pk_mul(v2f a, v2f b) {
    v2f d; asm("v_pk_mul_f32 %0, %1, %2" : "=v"(d) : "v"(a), "v"(b)); return d;
}
static __device__ __forceinline__ v2f pk_add(v2f a, v2f b) {
    v2f d; asm("v_pk_add_f32 %0, %1, %2" : "=v"(d) : "v"(a), "v"(b)); return d;
}
static __device__ __forceinline__ v2f pk_fma(v2f a, v2f b, v2f c) {
    v2f d; asm("v_pk_fma_f32 %0, %1, %2, %3" : "=v"(d) : "v"(a), "v"(b), "v"(c)); return d;
}

__global__ __launch_bounds__(NTHREADS, 6) void knn_pool_kernel(
    const float* __restrict__ src_f, const float* __restrict__ tgt_f,
    const float* __restrict__ src_c, const float* __restrict__ tgt_c,
    float* __restrict__ out)
{
    const int inst = blockIdx.x & 1;
    const float* __restrict__ feats  = inst ? tgt_f : src_f;
    const float* __restrict__ coords = inst ? tgt_c : src_c;
    float* __restrict__ outb = out + (size_t)inst * (size_t)N_PTS * (2 * C_FEAT);

    const int qblock = (blockIdx.x >> 1) * QPB;
    const int tid   = threadIdx.x;
    const int wave  = tid >> 6;
    const int lane  = tid & 63;
    const int lq    = lane >> 4;      // which query's list this lane belongs to
    const int lrank = lane & 15;      // rank within that list (valid if < KK)
    const bool inlist = (lrank < KK);
    const int upaddr = ((lane + 63) & 63) << 2;   // ds_bpermute addr: lane-1

    __shared__ __align__(16) float sx[TILE];
    __shared__ __align__(16) float sy[TILE];
    __shared__ __align__(16) float sz[TILE];

    const int q0 = qblock + wave * WQ;

    // Query coords + fp32 sq_i (frozen fma chain), splat to packed pairs.
    v2f qx2[WQ], qy2[WQ], qz2[WQ], qsq2[WQ];
    bool ingrp[WQ];
    #pragma unroll
    for (int q = 0; q < WQ; ++q) {
        const float x = coords[(q0 + q) * 3 + 0];
        const float y = coords[(q0 + q) * 3 + 1];
        const float z = coords[(q0 + q) * 3 + 2];
        const float s = __fmaf_rn(z, z, __fmaf_rn(y, y, __fmul_rn(x, x)));
        qx2[q]  = (v2f){x, x};
        qy2[q]  = (v2f){y, y};
        qz2[q]  = (v2f){z, z};
        qsq2[q] = (v2f){s, s};
        ingrp[q] = inlist && (lq == q);
    }
    const v2f mtwo = (v2f){-2.0f, -2.0f};

    // Lane-distributed sorted lists: lanes 16q..16q+10 hold (dist,idx),
    // ascending. worst[q] = current 11th-smallest (uniform, sgpr-resident).
    float ld = FLT_MAX;
    int   li = 0;
    float worst[WQ];
    #pragma unroll
    for (int q = 0; q < WQ; ++q) worst[q] = FLT_MAX;

    for (int t0 = 0; t0 < N_PTS; t0 += TILE) {
        __syncthreads();
        for (int p = tid; p < TILE; p += NTHREADS) {
            const float* cp = coords + (size_t)(t0 + p) * 3;
            sx[p] = cp[0]; sy[p] = cp[1]; sz[p] = cp[2];
        }
        __syncthreads();

        for (int b = 0; b < TILE; b += 128) {
            const int cp = b + (lane << 1);      // even candidate of the pair
            const v2f cx2 = *(const v2f*)&sx[cp];
            const v2f cy2 = *(const v2f*)&sy[cp];
            const v2f cz2 = *(const v2f*)&sz[cp];
            // csq = fma(z,z, fma(y,y, rn(x*x)))  [packed, per half]
            v2f csq2 = pk_mul(cx2, cx2);
            csq2 = pk_fma(cy2, cy2, csq2);
            csq2 = pk_fma(cz2, cz2, csq2);
            const int jbase = t0 + b;

            #pragma unroll
            for (int q = 0; q < WQ; ++q) {
                // dot chain (k = x,y,z ascending, same chain as sq).
                v2f dot2 = pk_mul(cx2, qx2[q]);
                dot2 = pk_fma(cy2, qy2[q], dot2);
                dot2 = pk_fma(cz2, qz2[q], dot2);
                const v2f sum2 = pk_add(qsq2[q], csq2);
                // d = rn(sum - 2*dot); 2*dot exact -> == rn(sum - rn(2*dot))
                const v2f d2 = pk_fma(dot2, mtwo, sum2);

                unsigned long long m0 = __ballot(d2.x < worst[q]);
                unsigned long long m1 = __ballot(d2.y < worst[q]);
                while (m0 | m1) {   // pop in ascending global candidate index
                    const int l0 = m0 ? (int)__builtin_ctzll(m0) : 64;
                    const int l1 = m1 ? (int)__builtin_ctzll(m1) : 64;
                    const bool even = (l0 <= l1);  // 2*l0 < 2*l1+1  <=>  l0<=l1
                    const int sl = even ? l0 : l1;
                    if (even) m0 &= m0 - 1; else m1 &= m1 - 1;
                    const float nd = __int_as_float(__builtin_amdgcn_readlane(
                        __float_as_int(even ? d2.x : d2.y), sl));
                    if (nd < worst[q]) {   // recheck: worst tightens in-loop
                        const int nj = jbase + 2 * sl + (even ? 0 : 1);
                        // Sorted insert across lanes 16q..16q+10:
                        // entries <= nd stay; entries > nd shift up one;
                        // first shifting lane takes (nd, nj); tail drops.
                        const float pld = __int_as_float(
                            __builtin_amdgcn_ds_bpermute(upaddr, __float_as_int(ld)));
                        const int   pli =
                            __builtin_amdgcn_ds_bpermute(upaddr, li);
                        if (ingrp[q] && ld > nd) {
                            const bool first = (lrank == 0) || (pld <= nd);
                            ld = first ? nd : pld;
                            li = first ? nj : pli;
                        }
                        worst[q] = __int_as_float(__builtin_amdgcn_readlane(
                            __float_as_int(ld), q * 16 + (KK - 1)));
                    }
                }
            }
        }
    }

    // Rank 0 dropped (self, or a -1ulp near-twin — positional, like ref).
    // Ranks 1..10 map to feature columns 0..9.
    float fv = -FLT_MAX;
    if (inlist && lrank >= 1)
        fv = feats[(size_t)li * C_FEAT + (lrank - 1)];
    #pragma unroll
    for (int off = 1; off < 16; off <<= 1)   // max within 16-lane group
        fv = fmaxf(fv, __shfl_xor(fv, off));

    #pragma unroll
    for (int q = 0; q < WQ; ++q) {
        const float M   = __shfl(fv, q * 16);
        const int   row = q0 + q;
        const float v   = feats[(size_t)row * C_FEAT + lane];
        outb[(size_t)row * (2 * C_FEAT) + lane]          = v;
        outb[(size_t)row * (2 * C_FEAT) + C_FEAT + lane] = M - v;
    }
}

extern "C" void kernel_launch(void* const* d_in, const int* in_sizes, int n_in,
                              void* d_out, int out_size, void* d_ws, size_t ws_size,
                              hipStream_t stream) {
    const float* src_f = (const float*)d_in[0];
    const float* tgt_f = (const float*)d_in[1];
    const float* src_c = (const float*)d_in[2];
    const float* tgt_c = (const float*)d_in[3];
    float* out = (float*)d_out;

    dim3 grid(2 * (N_PTS / QPB));   // 2048 blocks: even=src, odd=tgt
    dim3 block(NTHREADS);           // 256 threads = 4 waves
    hipLaunchKernelGGL(knn_pool_kernel, grid, block, 0, stream,
                       src_f, tgt_f, src_c, tgt_c, out);
}